// Round 1
// baseline (742.548 us; speedup 1.0000x reference)
//
#include <hip/hip_runtime.h>
#include <cstddef>

static constexpr int NX = 100000;
static constexpr int NC = 50000;
static constexpr int E  = 1000000;

// Generic fused linear: out_l = [relu](in @ W_l^T + b_l) for up to 3 layers,
// sharing one staged input tile. 64 rows/block, 256 threads, 4x4 per thread.
__global__ __launch_bounds__(256) void fused_linear(
    const float* __restrict__ in, int nrows,
    const float* __restrict__ W0, const float* __restrict__ b0, float* __restrict__ o0,
    const float* __restrict__ W1, const float* __restrict__ b1, float* __restrict__ o1,
    const float* __restrict__ W2, const float* __restrict__ b2, float* __restrict__ o2,
    int nlayers, int relu_mask)
{
    __shared__ float xT[64 * 68];   // xT[k][r] = in[row0+r][k], stride 68 keeps float4 16B-aligned
    __shared__ float Wt[64 * 68];   // Wt[k][j] = W[j][k]
    __shared__ float bs[64];
    const int t  = threadIdx.x;
    const int tr = t >> 4;          // 0..15 -> rows 4*tr..4*tr+3
    const int tc = t & 15;          // 0..15 -> cols 4*tc..4*tc+3
    const int row0 = blockIdx.x * 64;

    // stage x tile transposed
    #pragma unroll
    for (int p = 0; p < 4; ++p) {
        const int r   = p * 16 + tr;
        const int row = row0 + r;
        const int k4  = tc * 4;
        float4 v = make_float4(0.f, 0.f, 0.f, 0.f);
        if (row < nrows)
            v = *reinterpret_cast<const float4*>(in + (size_t)row * 64 + k4);
        xT[(k4 + 0) * 68 + r] = v.x;
        xT[(k4 + 1) * 68 + r] = v.y;
        xT[(k4 + 2) * 68 + r] = v.z;
        xT[(k4 + 3) * 68 + r] = v.w;
    }

    for (int l = 0; l < nlayers; ++l) {
        const float* W = (l == 0) ? W0 : (l == 1) ? W1 : W2;
        const float* b = (l == 0) ? b0 : (l == 1) ? b1 : b2;
        float*       o = (l == 0) ? o0 : (l == 1) ? o1 : o2;
        if (l) __syncthreads();   // prev compute done before Wt overwrite
        #pragma unroll
        for (int p = 0; p < 4; ++p) {
            const int j  = p * 16 + tr;
            const int k4 = tc * 4;
            float4 v = *reinterpret_cast<const float4*>(W + j * 64 + k4);
            Wt[(k4 + 0) * 68 + j] = v.x;
            Wt[(k4 + 1) * 68 + j] = v.y;
            Wt[(k4 + 2) * 68 + j] = v.z;
            Wt[(k4 + 3) * 68 + j] = v.w;
        }
        if (t < 64) bs[t] = b[t];
        __syncthreads();

        float acc[4][4];
        #pragma unroll
        for (int i = 0; i < 4; ++i)
            #pragma unroll
            for (int j = 0; j < 4; ++j) acc[i][j] = 0.f;

        #pragma unroll 8
        for (int k = 0; k < 64; ++k) {
            const float4 xv = *reinterpret_cast<const float4*>(&xT[k * 68 + tr * 4]);
            const float4 wv = *reinterpret_cast<const float4*>(&Wt[k * 68 + tc * 4]);
            const float xa[4] = {xv.x, xv.y, xv.z, xv.w};
            const float wa[4] = {wv.x, wv.y, wv.z, wv.w};
            #pragma unroll
            for (int i = 0; i < 4; ++i)
                #pragma unroll
                for (int j = 0; j < 4; ++j)
                    acc[i][j] = fmaf(xa[i], wa[j], acc[i][j]);
        }

        const bool relu = (relu_mask >> l) & 1;
        #pragma unroll
        for (int i = 0; i < 4; ++i) {
            const int row = row0 + tr * 4 + i;
            if (row < nrows) {
                float4 ov;
                ov.x = acc[i][0] + bs[tc * 4 + 0];
                ov.y = acc[i][1] + bs[tc * 4 + 1];
                ov.z = acc[i][2] + bs[tc * 4 + 2];
                ov.w = acc[i][3] + bs[tc * 4 + 3];
                if (relu) {
                    ov.x = fmaxf(ov.x, 0.f);
                    ov.y = fmaxf(ov.y, 0.f);
                    ov.z = fmaxf(ov.z, 0.f);
                    ov.w = fmaxf(ov.w, 0.f);
                }
                *reinterpret_cast<float4*>(o + (size_t)row * 64 + tc * 4) = ov;
            }
        }
    }
}

// One wave per edge (lane = feature). agg[dst] += h[src] with f32 atomics.
__global__ __launch_bounds__(256) void scatter_edges(
    const int* __restrict__ efs, const int* __restrict__ efd,
    const int* __restrict__ ebs, const int* __restrict__ ebd,
    const int* __restrict__ ecs, const int* __restrict__ ecd,
    const float* __restrict__ hff, const float* __restrict__ hbb,
    const float* __restrict__ hcx, float* __restrict__ agg)
{
    const int idx  = blockIdx.x * 256 + threadIdx.x;
    const int lane = idx & 63;
    const int e    = idx >> 6;
    if (e >= 3 * E) return;
    const int type = e / E;           // wave-uniform
    const int ei   = e - type * E;
    int src, dst;
    const float* h;
    if (type == 0)      { src = efs[ei]; dst = efd[ei]; h = hff; }
    else if (type == 1) { src = ebd[ei]; dst = ebs[ei]; h = hbb; } // direction swap!
    else                { src = ecs[ei]; dst = ecd[ei]; h = hcx; }
    atomicAdd(&agg[(size_t)dst * 64 + lane], h[(size_t)src * 64 + lane]);
}

extern "C" void kernel_launch(void* const* d_in, const int* in_sizes, int n_in,
                              void* d_out, int out_size, void* d_ws, size_t ws_size,
                              hipStream_t stream)
{
    const float* x   = (const float*)d_in[0];
    const float* c   = (const float*)d_in[1];
    const int*   efs = (const int*)d_in[2];
    const int*   efd = (const int*)d_in[3];
    const int*   ebs = (const int*)d_in[4];
    const int*   ebd = (const int*)d_in[5];
    const int*   ecs = (const int*)d_in[6];
    const int*   ecd = (const int*)d_in[7];
    const float* Wx  = (const float*)d_in[8];
    const float* bx  = (const float*)d_in[9];
    const float* Wc  = (const float*)d_in[10];
    const float* bc  = (const float*)d_in[11];
    const float* Wff = (const float*)d_in[12];
    const float* bff = (const float*)d_in[13];
    const float* Wbb = (const float*)d_in[14];
    const float* bbb = (const float*)d_in[15];
    const float* Wcx = (const float*)d_in[16];
    const float* bcx = (const float*)d_in[17];
    const float* Wp  = (const float*)d_in[18];
    const float* bp  = (const float*)d_in[19];

    float* out_x = (float*)d_out;                    // [NX*64]; doubles as agg buffer
    float* out_c = (float*)d_out + (size_t)NX * 64;  // [NC*64]
    float* hff = (float*)d_ws;
    float* hbb = hff + (size_t)NX * 64;
    float* hcx = hbb + (size_t)NX * 64;

    // 1) x-side node GEMMs: agg = relu(x Wx^T + bx); h_ff; h_bb
    fused_linear<<<(NX + 63) / 64, 256, 0, stream>>>(
        x, NX, Wx, bx, out_x, Wff, bff, hff, Wbb, bbb, hbb, 3, 7);
    // 2) c-side node GEMMs: out_c = relu(c Wc^T + bc); h_cx
    fused_linear<<<(NC + 63) / 64, 256, 0, stream>>>(
        c, NC, Wc, bc, out_c, Wcx, bcx, hcx, nullptr, nullptr, nullptr, 2, 3);
    // 3) edge scatter-add into agg (out_x region)
    scatter_edges<<<(3 * E * 64) / 256, 256, 0, stream>>>(
        efs, efd, ebs, ebd, ecs, ecd, hff, hbb, hcx, out_x);
    // 4) pool GEMM, in-place on agg -> out_x
    fused_linear<<<(NX + 63) / 64, 256, 0, stream>>>(
        out_x, NX, Wp, bp, out_x, nullptr, nullptr, nullptr, nullptr, nullptr, nullptr, 1, 0);
}

// Round 2
// 586.618 us; speedup vs baseline: 1.2658x; 1.2658x over previous
//
#include <hip/hip_runtime.h>
#include <cstddef>

static constexpr int NX = 100000;
static constexpr int NC = 50000;
static constexpr int E  = 1000000;
static constexpr int E3 = 3 * E;
static constexpr int SCAN_NB = (NX + 1023) / 1024;   // 98

// ---------------- GEMM: out_l = [relu](in @ W_l^T + b_l), up to 3 layers ----------------
__global__ __launch_bounds__(256) void fused_linear(
    const float* __restrict__ in, int nrows,
    const float* __restrict__ W0, const float* __restrict__ b0, float* __restrict__ o0,
    const float* __restrict__ W1, const float* __restrict__ b1, float* __restrict__ o1,
    const float* __restrict__ W2, const float* __restrict__ b2, float* __restrict__ o2,
    int nlayers, int relu_mask)
{
    __shared__ float xT[64 * 68];
    __shared__ float Wt[64 * 68];
    __shared__ float bs[64];
    const int t  = threadIdx.x;
    const int tr = t >> 4;
    const int tc = t & 15;
    const int row0 = blockIdx.x * 64;

    #pragma unroll
    for (int p = 0; p < 4; ++p) {
        const int r   = p * 16 + tr;
        const int row = row0 + r;
        const int k4  = tc * 4;
        float4 v = make_float4(0.f, 0.f, 0.f, 0.f);
        if (row < nrows)
            v = *reinterpret_cast<const float4*>(in + (size_t)row * 64 + k4);
        xT[(k4 + 0) * 68 + r] = v.x;
        xT[(k4 + 1) * 68 + r] = v.y;
        xT[(k4 + 2) * 68 + r] = v.z;
        xT[(k4 + 3) * 68 + r] = v.w;
    }

    for (int l = 0; l < nlayers; ++l) {
        const float* W = (l == 0) ? W0 : (l == 1) ? W1 : W2;
        const float* b = (l == 0) ? b0 : (l == 1) ? b1 : b2;
        float*       o = (l == 0) ? o0 : (l == 1) ? o1 : o2;
        if (l) __syncthreads();
        #pragma unroll
        for (int p = 0; p < 4; ++p) {
            const int j  = p * 16 + tr;
            const int k4 = tc * 4;
            float4 v = *reinterpret_cast<const float4*>(W + j * 64 + k4);
            Wt[(k4 + 0) * 68 + j] = v.x;
            Wt[(k4 + 1) * 68 + j] = v.y;
            Wt[(k4 + 2) * 68 + j] = v.z;
            Wt[(k4 + 3) * 68 + j] = v.w;
        }
        if (t < 64) bs[t] = b[t];
        __syncthreads();

        float acc[4][4];
        #pragma unroll
        for (int i = 0; i < 4; ++i)
            #pragma unroll
            for (int j = 0; j < 4; ++j) acc[i][j] = 0.f;

        #pragma unroll 8
        for (int k = 0; k < 64; ++k) {
            const float4 xv = *reinterpret_cast<const float4*>(&xT[k * 68 + tr * 4]);
            const float4 wv = *reinterpret_cast<const float4*>(&Wt[k * 68 + tc * 4]);
            const float xa[4] = {xv.x, xv.y, xv.z, xv.w};
            const float wa[4] = {wv.x, wv.y, wv.z, wv.w};
            #pragma unroll
            for (int i = 0; i < 4; ++i)
                #pragma unroll
                for (int j = 0; j < 4; ++j)
                    acc[i][j] = fmaf(xa[i], wa[j], acc[i][j]);
        }

        const bool relu = (relu_mask >> l) & 1;
        #pragma unroll
        for (int i = 0; i < 4; ++i) {
            const int row = row0 + tr * 4 + i;
            if (row < nrows) {
                float4 ov;
                ov.x = acc[i][0] + bs[tc * 4 + 0];
                ov.y = acc[i][1] + bs[tc * 4 + 1];
                ov.z = acc[i][2] + bs[tc * 4 + 2];
                ov.w = acc[i][3] + bs[tc * 4 + 3];
                if (relu) {
                    ov.x = fmaxf(ov.x, 0.f);
                    ov.y = fmaxf(ov.y, 0.f);
                    ov.z = fmaxf(ov.z, 0.f);
                    ov.w = fmaxf(ov.w, 0.f);
                }
                *reinterpret_cast<float4*>(o + (size_t)row * 64 + tc * 4) = ov;
            }
        }
    }
}

// ---------------- CSR build ----------------
__global__ __launch_bounds__(256) void zero_ints(int* __restrict__ p, int n)
{
    int i = blockIdx.x * 256 + threadIdx.x;
    if (i < n) p[i] = 0;
}

__global__ __launch_bounds__(256) void edge_hist(
    const int* __restrict__ efd, const int* __restrict__ ebs, const int* __restrict__ ecd,
    int* __restrict__ counts)
{
    int i = blockIdx.x * 256 + threadIdx.x;
    if (i >= E3) return;
    int d;
    if (i < E)       d = efd[i];
    else if (i < 2*E) d = ebs[i - E];      // '<-' edge: scatter target is stored src
    else              d = ecd[i - 2*E];
    atomicAdd(&counts[d], 1);
}

__global__ __launch_bounds__(1024) void scan_reduce(
    const int* __restrict__ counts, int* __restrict__ blocksums)
{
    __shared__ int s[1024];
    int i = blockIdx.x * 1024 + threadIdx.x;
    s[threadIdx.x] = (i < NX) ? counts[i] : 0;
    __syncthreads();
    for (int st = 512; st > 0; st >>= 1) {
        if (threadIdx.x < st) s[threadIdx.x] += s[threadIdx.x + st];
        __syncthreads();
    }
    if (threadIdx.x == 0) blocksums[blockIdx.x] = s[0];
}

__global__ __launch_bounds__(128) void scan_blocksums(int* __restrict__ blocksums)
{
    __shared__ int s[128];
    int v = (threadIdx.x < SCAN_NB) ? blocksums[threadIdx.x] : 0;
    s[threadIdx.x] = v;
    __syncthreads();
    for (int st = 1; st < 128; st <<= 1) {
        int t = (threadIdx.x >= st) ? s[threadIdx.x - st] : 0;
        __syncthreads();
        s[threadIdx.x] += t;
        __syncthreads();
    }
    if (threadIdx.x < SCAN_NB) blocksums[threadIdx.x] = s[threadIdx.x] - v;  // exclusive
}

__global__ __launch_bounds__(1024) void scan_downsweep(
    const int* __restrict__ counts, const int* __restrict__ blocksums,
    int* __restrict__ offsets, int* __restrict__ cursor)
{
    __shared__ int s[1024];
    int i = blockIdx.x * 1024 + threadIdx.x;
    int v = (i < NX) ? counts[i] : 0;
    s[threadIdx.x] = v;
    __syncthreads();
    for (int st = 1; st < 1024; st <<= 1) {
        int t = (threadIdx.x >= st) ? s[threadIdx.x - st] : 0;
        __syncthreads();
        s[threadIdx.x] += t;
        __syncthreads();
    }
    int excl = s[threadIdx.x] - v + blocksums[blockIdx.x];
    if (i < NX) { offsets[i] = excl; cursor[i] = excl; }
    if (i == NX - 1) offsets[NX] = excl + v;
}

__global__ __launch_bounds__(256) void edge_fill(
    const int* __restrict__ efs, const int* __restrict__ efd,
    const int* __restrict__ ebs, const int* __restrict__ ebd,
    const int* __restrict__ ecs, const int* __restrict__ ecd,
    int* __restrict__ cursor, int* __restrict__ csr)
{
    int i = blockIdx.x * 256 + threadIdx.x;
    if (i >= E3) return;
    int dst, sg;
    if (i < E)        { dst = efd[i];       sg = efs[i]; }
    else if (i < 2*E) { dst = ebs[i - E];   sg = NX + ebd[i - E]; }   // direction swap
    else              { dst = ecd[i - 2*E]; sg = 2 * NX + ecs[i - 2*E]; }
    int pos = atomicAdd(&cursor[dst], 1);
    csr[pos] = sg;
}

// one wave per dst row; lane = feature; agg starts as self_x (already in place)
__global__ __launch_bounds__(256) void gather_agg(
    const int* __restrict__ offsets, const int* __restrict__ csr,
    const float* __restrict__ h_all, float* __restrict__ agg)
{
    const int wave = (blockIdx.x * 256 + threadIdx.x) >> 6;
    const int lane = threadIdx.x & 63;
    if (wave >= NX) return;
    const int start = offsets[wave];
    const int end   = offsets[wave + 1];
    float acc = agg[(size_t)wave * 64 + lane];
    int i = start;
    for (; i + 4 <= end; i += 4) {
        const int s0 = csr[i], s1 = csr[i + 1], s2 = csr[i + 2], s3 = csr[i + 3];
        const float v0 = h_all[(size_t)s0 * 64 + lane];
        const float v1 = h_all[(size_t)s1 * 64 + lane];
        const float v2 = h_all[(size_t)s2 * 64 + lane];
        const float v3 = h_all[(size_t)s3 * 64 + lane];
        acc += (v0 + v1) + (v2 + v3);
    }
    for (; i < end; ++i)
        acc += h_all[(size_t)csr[i] * 64 + lane];
    agg[(size_t)wave * 64 + lane] = acc;
}

// fallback (round-1 path): per-edge atomics
__global__ __launch_bounds__(256) void scatter_edges(
    const int* __restrict__ efs, const int* __restrict__ efd,
    const int* __restrict__ ebs, const int* __restrict__ ebd,
    const int* __restrict__ ecs, const int* __restrict__ ecd,
    const float* __restrict__ hff, const float* __restrict__ hbb,
    const float* __restrict__ hcx, float* __restrict__ agg)
{
    const int idx  = blockIdx.x * 256 + threadIdx.x;
    const int lane = idx & 63;
    const int e    = idx >> 6;
    if (e >= E3) return;
    const int type = e / E;
    const int ei   = e - type * E;
    int src, dst;
    const float* h;
    if (type == 0)      { src = efs[ei]; dst = efd[ei]; h = hff; }
    else if (type == 1) { src = ebd[ei]; dst = ebs[ei]; h = hbb; }
    else                { src = ecs[ei]; dst = ecd[ei]; h = hcx; }
    atomicAdd(&agg[(size_t)dst * 64 + lane], h[(size_t)src * 64 + lane]);
}

extern "C" void kernel_launch(void* const* d_in, const int* in_sizes, int n_in,
                              void* d_out, int out_size, void* d_ws, size_t ws_size,
                              hipStream_t stream)
{
    const float* x   = (const float*)d_in[0];
    const float* c   = (const float*)d_in[1];
    const int*   efs = (const int*)d_in[2];
    const int*   efd = (const int*)d_in[3];
    const int*   ebs = (const int*)d_in[4];
    const int*   ebd = (const int*)d_in[5];
    const int*   ecs = (const int*)d_in[6];
    const int*   ecd = (const int*)d_in[7];
    const float* Wx  = (const float*)d_in[8];
    const float* bx  = (const float*)d_in[9];
    const float* Wc  = (const float*)d_in[10];
    const float* bc  = (const float*)d_in[11];
    const float* Wff = (const float*)d_in[12];
    const float* bff = (const float*)d_in[13];
    const float* Wbb = (const float*)d_in[14];
    const float* bbb = (const float*)d_in[15];
    const float* Wcx = (const float*)d_in[16];
    const float* bcx = (const float*)d_in[17];
    const float* Wp  = (const float*)d_in[18];
    const float* bp  = (const float*)d_in[19];

    float* out_x = (float*)d_out;                    // [NX*64]; also agg buffer
    float* out_c = (float*)d_out + (size_t)NX * 64;  // [NC*64]

    // ws layout: h_all (2NX+NC rows x 64 f32), then int arrays
    float* h_all = (float*)d_ws;
    float* hff = h_all;
    float* hbb = h_all + (size_t)NX * 64;
    float* hcx = h_all + (size_t)2 * NX * 64;
    const size_t h_floats = (size_t)(2 * NX + NC) * 64;

    int* counts    = (int*)(h_all + h_floats);
    int* offsets   = counts + NX;            // NX+1
    int* cursor    = offsets + NX + 1;       // NX
    int* blocksums = cursor + NX;            // 128
    int* csr       = blocksums + 128;        // 3E
    const size_t need_bytes = h_floats * 4 + ((size_t)3 * NX + 1 + 128 + (size_t)E3) * 4;

    // node GEMMs (both paths need these)
    fused_linear<<<(NX + 63) / 64, 256, 0, stream>>>(
        x, NX, Wx, bx, out_x, Wff, bff, hff, Wbb, bbb, hbb, 3, 7);
    fused_linear<<<(NC + 63) / 64, 256, 0, stream>>>(
        c, NC, Wc, bc, out_c, Wcx, bcx, hcx, nullptr, nullptr, nullptr, 2, 3);

    if (ws_size >= need_bytes) {
        // CSR build + gather
        zero_ints<<<(NX + 255) / 256, 256, 0, stream>>>(counts, NX);
        edge_hist<<<(E3 + 255) / 256, 256, 0, stream>>>(efd, ebs, ecd, counts);
        scan_reduce<<<SCAN_NB, 1024, 0, stream>>>(counts, blocksums);
        scan_blocksums<<<1, 128, 0, stream>>>(blocksums);
        scan_downsweep<<<SCAN_NB, 1024, 0, stream>>>(counts, blocksums, offsets, cursor);
        edge_fill<<<(E3 + 255) / 256, 256, 0, stream>>>(efs, efd, ebs, ebd, ecs, ecd, cursor, csr);
        gather_agg<<<((size_t)NX * 64 + 255) / 256, 256, 0, stream>>>(offsets, csr, h_all, out_x);
    } else {
        scatter_edges<<<((size_t)E3 * 64 + 255) / 256, 256, 0, stream>>>(
            efs, efd, ebs, ebd, ecs, ecd, hff, hbb, hcx, out_x);
    }

    // pool GEMM in-place on agg -> out_x
    fused_linear<<<(NX + 63) / 64, 256, 0, stream>>>(
        out_x, NX, Wp, bp, out_x, nullptr, nullptr, nullptr, nullptr, nullptr, nullptr, 1, 0);
}